// Round 5
// baseline (1677.231 us; speedup 1.0000x reference)
//
#include <hip/hip_runtime.h>
#include <hip/hip_bf16.h>

// GestureCNNLSTM: conv1(1->16,3x3,p1)+relu+pool2 -> conv2(16->32,3x3,p1)+relu+pool2
//  -> flatten 192 -> gx GEMM (+b_ih+b_hh) -> 512-step LSTM (H=256) -> 64-dim classifier.
// x [128][512][13][10] f32, out [128][64] f32. feat/gx carried as f16 (159.4 MB ws).

typedef _Float16 half2v __attribute__((ext_vector_type(2)));
typedef _Float16 f16x8 __attribute__((ext_vector_type(8)));
typedef float f32x4 __attribute__((ext_vector_type(4)));

__device__ __forceinline__ float dot2f16(half2v a, half2v b, float c) {
#if defined(__has_builtin)
#if __has_builtin(__builtin_amdgcn_fdot2)
    return __builtin_amdgcn_fdot2(a, b, c, false);
#else
    return c + (float)a.x * (float)b.x + (float)a.y * (float)b.y;
#endif
#else
    return c + (float)a.x * (float)b.x + (float)a.y * (float)b.y;
#endif
}

__device__ __forceinline__ unsigned int packf2(const float* p) {
    half2v hv;
    hv.x = (_Float16)p[0];
    hv.y = (_Float16)p[1];
    return __builtin_bit_cast(unsigned int, hv);
}

__device__ __forceinline__ half2v bch2(unsigned int u) {
    return __builtin_bit_cast(half2v, u);
}

// ---------------- Kernel A: fused conv1+pool1+conv2+pool2 ----------------
__global__ __launch_bounds__(256) void conv_kernel(
    const float* __restrict__ x,     // [65536][13][10]
    const float* __restrict__ c1w,   // [16][1][3][3]
    const float* __restrict__ c1b,   // [16]
    const float* __restrict__ c2w,   // [32][16][3][3]
    const float* __restrict__ c2b,   // [32]
    _Float16* __restrict__ feat)     // [65536][192]
{
    __shared__ float w1t[9 * 16];
    __shared__ float b1s[16];
    __shared__ float w2t[16 * 9 * 32];
    __shared__ float b2s[32];
    __shared__ float xp[4][14 * 12];
    __shared__ float p1p[4][16 * 8 * 7];

    const int tid = threadIdx.x;

    for (int idx = tid; idx < 144; idx += 256) {
        int oc = idx / 9, k = idx % 9;
        w1t[k * 16 + oc] = c1w[idx];
    }
    if (tid < 16) b1s[tid] = c1b[tid];
    for (int idx = tid; idx < 4608; idx += 256) {
        int oc = idx / 144, ic = (idx / 9) % 16, k = idx % 9;
        w2t[(ic * 9 + k) * 32 + oc] = c2w[idx];
    }
    if (tid < 32) b2s[tid] = c2b[tid];

    const int w = tid >> 6;
    const int lane = tid & 63;
    const int img = blockIdx.x * 4 + w;

    for (int i = lane; i < 14 * 12; i += 64) xp[w][i] = 0.f;
    for (int i = lane; i < 16 * 8 * 7; i += 64) p1p[w][i] = 0.f;
    __syncthreads();

    const float* xin = x + (size_t)img * 130;
    for (int i = lane; i < 130; i += 64) {
        int r = i / 10, c = i % 10;
        xp[w][(r + 1) * 12 + (c + 1)] = xin[i];
    }
    __syncthreads();

    {
        const int oc = lane & 15, q = lane >> 4;
        #pragma unroll
        for (int i = 0; i < 8; i++) {
            int pos = i * 4 + q;
            if (pos < 30) {
                int ph = pos / 5, pw = pos % 5;
                float cmax = -1e30f;
                #pragma unroll
                for (int pt = 0; pt < 4; pt++) {
                    int Y = 2 * ph + (pt >> 1), X = 2 * pw + (pt & 1);
                    float s = 0.f;
                    #pragma unroll
                    for (int k = 0; k < 9; k++) {
                        int dy = k / 3, dx = k % 3;
                        s += w1t[k * 16 + oc] * xp[w][(Y + dy) * 12 + X + dx];
                    }
                    cmax = fmaxf(cmax, s);
                }
                p1p[w][(oc * 8 + ph + 1) * 7 + (pw + 1)] = fmaxf(0.f, cmax + b1s[oc]);
            }
        }
    }
    __syncthreads();

    {
        const int oc = lane & 31, pw2 = lane >> 5;
        float acc[3][4];
        #pragma unroll
        for (int a = 0; a < 3; a++)
            #pragma unroll
            for (int b = 0; b < 4; b++) acc[a][b] = 0.f;

        for (int ic = 0; ic < 16; ic++) {
            #pragma unroll
            for (int k = 0; k < 9; k++) {
                int dy = k / 3, dx = k % 3;
                float wv = w2t[(ic * 9 + k) * 32 + oc];
                #pragma unroll
                for (int ph2 = 0; ph2 < 3; ph2++) {
                    #pragma unroll
                    for (int pt = 0; pt < 4; pt++) {
                        int y = 2 * ph2 + (pt >> 1) + dy;
                        int xx = 2 * pw2 + (pt & 1) + dx;
                        acc[ph2][pt] += wv * p1p[w][(ic * 8 + y) * 7 + xx];
                    }
                }
            }
        }
        float bias = b2s[oc];
        _Float16* fo = feat + (size_t)img * 192;
        #pragma unroll
        for (int ph2 = 0; ph2 < 3; ph2++) {
            float m = fmaxf(fmaxf(acc[ph2][0], acc[ph2][1]),
                            fmaxf(acc[ph2][2], acc[ph2][3]));
            fo[oc * 6 + ph2 * 2 + pw2] = (_Float16)fmaxf(0.f, m + bias);
        }
    }
}

// ---------------- Kernel B: gx = feat @ W_ih^T + bias via MFMA f16 ----------
__global__ __launch_bounds__(256) void gemm_gx_kernel(
    const _Float16* __restrict__ feat,  // [65536][192]
    const float* __restrict__ Wih,      // [1024][192]
    const float* __restrict__ bih,
    const float* __restrict__ bhh,
    _Float16* __restrict__ gx)          // [65536][1024]
{
    __shared__ uint4 As4[64][25];   // 25.6 KB, row stride 400 B
    __shared__ uint4 Bs4[64][25];   // 25.6 KB

    const int tid = threadIdx.x;
    const int n0 = blockIdx.x * 64;
    const int m0 = blockIdx.y * 64;

    #pragma unroll
    for (int it = 0; it < 6; it++) {
        int q = tid + it * 256;
        int m = q / 24, c = q % 24;
        As4[m][c] = *(const uint4*)(feat + (size_t)(m0 + m) * 192 + c * 8);
    }
    unsigned int* Bu = (unsigned int*)Bs4;
    #pragma unroll
    for (int it = 0; it < 24; it++) {
        int q = tid + it * 256;
        int n = q / 96, p = q % 96;
        Bu[n * 100 + p] = packf2(Wih + (size_t)(n0 + n) * 192 + 2 * p);
    }
    __syncthreads();

    const int wv = tid >> 6;
    const int lane = tid & 63;
    const int lm = lane & 15;
    const int lk = lane >> 4;

    f32x4 acc[4] = {{0.f, 0.f, 0.f, 0.f}, {0.f, 0.f, 0.f, 0.f},
                    {0.f, 0.f, 0.f, 0.f}, {0.f, 0.f, 0.f, 0.f}};

    #pragma unroll
    for (int ks = 0; ks < 6; ks++) {
        f16x8 a = __builtin_bit_cast(f16x8, As4[wv * 16 + lm][ks * 4 + lk]);
        #pragma unroll
        for (int j = 0; j < 4; j++) {
            f16x8 b = __builtin_bit_cast(f16x8, Bs4[j * 16 + lm][ks * 4 + lk]);
            acc[j] = __builtin_amdgcn_mfma_f32_16x16x32_f16(a, b, acc[j], 0, 0, 0);
        }
    }

    #pragma unroll
    for (int j = 0; j < 4; j++) {
        int n = n0 + j * 16 + lm;
        float bias = bih[n] + bhh[n];
        #pragma unroll
        for (int i = 0; i < 4; i++) {
            int m = m0 + wv * 16 + lk * 4 + i;
            gx[(size_t)m * 1024 + n] = (_Float16)(acc[j][i] + bias);
        }
    }
}

// ---------------- Kernel C: 512-step LSTM + classifier ----------------
// 128 blocks x 1024 threads (16 waves, 4/SIMD, VGPR cap 128 by design).
// Thread t owns ONE gate row t (i rows 0..255, f 256.., g 512.., o 768..):
//   weights: pairs 0..91 in regs (92 VGPR), pairs 92..127 in LDS uint4 [9][1024].
// h distribution: one ds_read_b64 per wave (lane l -> h[4l..4l+3]), then
// v_readlane broadcasts each pair to SGPR -> v_dot2 SGPR operand. No LDS
// broadcast traffic, no spills. Gate exchange via xg[1024] (4 KB).
__global__ __launch_bounds__(1024, 4) void lstm_kernel(
    const _Float16* __restrict__ gx, // [128][512][1024]
    const float* __restrict__ Whh,   // [1024][256]
    const float* __restrict__ clsw,  // [64][256]
    const float* __restrict__ clsb,  // [64]
    float* __restrict__ out)         // [128][64]
{
    __shared__ uint4 wl4[9][1024];                     // 144 KB: pairs 92..127
    __shared__ __align__(16) _Float16 hbuf[2][256];    // 1 KB
    __shared__ float xg[1024];                         // 4 KB

    const int t = threadIdx.x;
    const int b = blockIdx.x;
    const int lane = t & 63;

    const float* wrow = Whh + (size_t)t * 256;

    half2v wr[92];
    #pragma unroll
    for (int p = 0; p < 92; p++) wr[p] = bch2(packf2(&wrow[2 * p]));
    #pragma unroll
    for (int ch = 0; ch < 9; ch++) {
        uint4 v;
        v.x = packf2(&wrow[184 + 8 * ch + 0]);
        v.y = packf2(&wrow[184 + 8 * ch + 2]);
        v.z = packf2(&wrow[184 + 8 * ch + 4]);
        v.w = packf2(&wrow[184 + 8 * ch + 6]);
        wl4[ch][t] = v;
    }
    if (t < 256) hbuf[0][t] = (_Float16)0.f;
    __syncthreads();

    float c = 0.f;
    int cur = 0;
    const _Float16* gxb = gx + (size_t)b * 512 * 1024;
    float ga = (float)gxb[t];

    for (int step = 0; step < 512; step++) {
        const _Float16* gxn = gxb + (size_t)((step + 1) & 511) * 1024;
        _Float16 na = gxn[t];

        // wave-wide h slice: lane l holds h pairs 2l (x) and 2l+1 (y)
        uint2 vh = *(const uint2*)&hbuf[cur][lane * 4];

        float acc0 = ga, acc1 = 0.f;
        // register-resident pairs 0..91
        #pragma unroll
        for (int p = 0; p < 92; p += 2) {
            unsigned int h0 = __builtin_amdgcn_readlane(vh.x, p >> 1);
            unsigned int h1 = __builtin_amdgcn_readlane(vh.y, p >> 1);
            acc0 = dot2f16(wr[p], bch2(h0), acc0);
            acc1 = dot2f16(wr[p + 1], bch2(h1), acc1);
        }
        // LDS-resident pairs 92..127
        #pragma unroll
        for (int ch = 0; ch < 9; ch++) {
            uint4 u = wl4[ch][t];
            int p = 92 + 4 * ch;   // even
            unsigned int h0 = __builtin_amdgcn_readlane(vh.x, (p >> 1) + 0);
            unsigned int h1 = __builtin_amdgcn_readlane(vh.y, (p >> 1) + 0);
            unsigned int h2 = __builtin_amdgcn_readlane(vh.x, (p >> 1) + 1);
            unsigned int h3 = __builtin_amdgcn_readlane(vh.y, (p >> 1) + 1);
            acc0 = dot2f16(bch2(u.x), bch2(h0), acc0);
            acc1 = dot2f16(bch2(u.y), bch2(h1), acc1);
            acc0 = dot2f16(bch2(u.z), bch2(h2), acc0);
            acc1 = dot2f16(bch2(u.w), bch2(h3), acc1);
        }
        xg[t] = acc0 + acc1;
        __syncthreads();

        if (t < 256) {
            float i_ = 1.f / (1.f + __expf(-xg[t]));
            float f_ = 1.f / (1.f + __expf(-xg[t + 256]));
            float g_ = 1.f - 2.f / (__expf(2.f * xg[t + 512]) + 1.f);
            float o_ = 1.f / (1.f + __expf(-xg[t + 768]));
            c = f_ * c + i_ * g_;
            float th = 1.f - 2.f / (__expf(2.f * c) + 1.f);
            float h = o_ * th;
            hbuf[cur ^ 1][t] = (_Float16)h;
        }
        __syncthreads();
        cur ^= 1;
        ga = (float)na;
    }

    if (t < 64) {
        const float* cw = clsw + t * 256;
        float s = clsb[t];
        for (int k = 0; k < 256; k++) s += cw[k] * (float)hbuf[cur][k];
        out[b * 64 + t] = s;
    }
}

extern "C" void kernel_launch(void* const* d_in, const int* in_sizes, int n_in,
                              void* d_out, int out_size, void* d_ws, size_t ws_size,
                              hipStream_t stream) {
    const float* x    = (const float*)d_in[0];
    const float* c1w  = (const float*)d_in[1];
    const float* c1b  = (const float*)d_in[2];
    const float* c2w  = (const float*)d_in[3];
    const float* c2b  = (const float*)d_in[4];
    const float* Wih  = (const float*)d_in[5];
    const float* bih  = (const float*)d_in[6];
    const float* Whh  = (const float*)d_in[7];
    const float* bhh  = (const float*)d_in[8];
    const float* clsw = (const float*)d_in[9];
    const float* clsb = (const float*)d_in[10];

    _Float16* feat = (_Float16*)d_ws;                   // 65536*192*2B = 25.2 MB
    _Float16* gx   = feat + (size_t)65536 * 192;        // 65536*1024*2B = 134.2 MB
    float* outp = (float*)d_out;

    hipLaunchKernelGGL(conv_kernel, dim3(16384), dim3(256), 0, stream,
                       x, c1w, c1b, c2w, c2b, feat);
    hipLaunchKernelGGL(gemm_gx_kernel, dim3(16, 1024), dim3(256), 0, stream,
                       feat, Wih, bih, bhh, gx);
    hipLaunchKernelGGL(lstm_kernel, dim3(128), dim3(1024), 0, stream,
                       gx, Whh, clsw, clsb, outp);
}

// Round 6
// 1292.991 us; speedup vs baseline: 1.2972x; 1.2972x over previous
//
#include <hip/hip_runtime.h>
#include <hip/hip_bf16.h>

// GestureCNNLSTM: conv1(1->16,3x3,p1)+relu+pool2 -> conv2(16->32,3x3,p1)+relu+pool2
//  -> flatten 192 -> gx GEMM (+b_ih+b_hh) -> 512-step LSTM (H=256) -> 64-dim classifier.
// x [128][512][13][10] f32, out [128][64] f32. feat/gx f16 in ws (159.6 MB).
//
// LSTM weight residency (per gate row, 128 f16 pairs), sized to the compiler's
// observed 128-VGPR cap at 512 threads: 36 pairs LDS (144 KB) + 40 pairs regs
// (80 VGPR) + 52 pairs streamed per step from a pre-packed f16 buffer (L2-hot).

typedef _Float16 half2v __attribute__((ext_vector_type(2)));
typedef _Float16 f16x8 __attribute__((ext_vector_type(8)));
typedef float f32x4 __attribute__((ext_vector_type(4)));

__device__ __forceinline__ float dot2f16(half2v a, half2v b, float c) {
#if defined(__has_builtin)
#if __has_builtin(__builtin_amdgcn_fdot2)
    return __builtin_amdgcn_fdot2(a, b, c, false);
#else
    return c + (float)a.x * (float)b.x + (float)a.y * (float)b.y;
#endif
#else
    return c + (float)a.x * (float)b.x + (float)a.y * (float)b.y;
#endif
}

__device__ __forceinline__ unsigned int packf2(const float* p) {
    half2v hv;
    hv.x = (_Float16)p[0];
    hv.y = (_Float16)p[1];
    return __builtin_bit_cast(unsigned int, hv);
}

__device__ __forceinline__ half2v bch2(unsigned int u) {
    return __builtin_bit_cast(half2v, u);
}

__device__ __forceinline__ uint4 pack8(const float* p) {
    uint4 v;
    v.x = packf2(p + 0);
    v.y = packf2(p + 2);
    v.z = packf2(p + 4);
    v.w = packf2(p + 6);
    return v;
}

// ---------------- Kernel P: pre-pack W_hh stream section to f16 ----------------
// sw[c][r] (c=0..12, r=0..1023) = pairs 76+4c..76+4c+3 of row r (f32 elems 152+8c..+7)
__global__ __launch_bounds__(256) void prepack_kernel(
    const float* __restrict__ Whh, uint4* __restrict__ sw)
{
    int idx = blockIdx.x * 256 + threadIdx.x;
    if (idx < 13 * 1024) {
        int c = idx >> 10, r = idx & 1023;
        sw[idx] = pack8(Whh + (size_t)r * 256 + 152 + 8 * c);
    }
}

// ---------------- Kernel A: fused conv1+pool1+conv2+pool2 ----------------
__global__ __launch_bounds__(256) void conv_kernel(
    const float* __restrict__ x,     // [65536][13][10]
    const float* __restrict__ c1w,   // [16][1][3][3]
    const float* __restrict__ c1b,   // [16]
    const float* __restrict__ c2w,   // [32][16][3][3]
    const float* __restrict__ c2b,   // [32]
    _Float16* __restrict__ feat)     // [65536][192]
{
    __shared__ float w1t[9 * 16];
    __shared__ float b1s[16];
    __shared__ float w2t[16 * 9 * 32];
    __shared__ float b2s[32];
    __shared__ float xp[4][14 * 12];
    __shared__ float p1p[4][16 * 8 * 7];

    const int tid = threadIdx.x;

    for (int idx = tid; idx < 144; idx += 256) {
        int oc = idx / 9, k = idx % 9;
        w1t[k * 16 + oc] = c1w[idx];
    }
    if (tid < 16) b1s[tid] = c1b[tid];
    for (int idx = tid; idx < 4608; idx += 256) {
        int oc = idx / 144, ic = (idx / 9) % 16, k = idx % 9;
        w2t[(ic * 9 + k) * 32 + oc] = c2w[idx];
    }
    if (tid < 32) b2s[tid] = c2b[tid];

    const int w = tid >> 6;
    const int lane = tid & 63;
    const int img = blockIdx.x * 4 + w;

    for (int i = lane; i < 14 * 12; i += 64) xp[w][i] = 0.f;
    for (int i = lane; i < 16 * 8 * 7; i += 64) p1p[w][i] = 0.f;
    __syncthreads();

    const float* xin = x + (size_t)img * 130;
    for (int i = lane; i < 130; i += 64) {
        int r = i / 10, c = i % 10;
        xp[w][(r + 1) * 12 + (c + 1)] = xin[i];
    }
    __syncthreads();

    {
        const int oc = lane & 15, q = lane >> 4;
        #pragma unroll
        for (int i = 0; i < 8; i++) {
            int pos = i * 4 + q;
            if (pos < 30) {
                int ph = pos / 5, pw = pos % 5;
                float cmax = -1e30f;
                #pragma unroll
                for (int pt = 0; pt < 4; pt++) {
                    int Y = 2 * ph + (pt >> 1), X = 2 * pw + (pt & 1);
                    float s = 0.f;
                    #pragma unroll
                    for (int k = 0; k < 9; k++) {
                        int dy = k / 3, dx = k % 3;
                        s += w1t[k * 16 + oc] * xp[w][(Y + dy) * 12 + X + dx];
                    }
                    cmax = fmaxf(cmax, s);
                }
                p1p[w][(oc * 8 + ph + 1) * 7 + (pw + 1)] = fmaxf(0.f, cmax + b1s[oc]);
            }
        }
    }
    __syncthreads();

    {
        const int oc = lane & 31, pw2 = lane >> 5;
        float acc[3][4];
        #pragma unroll
        for (int a = 0; a < 3; a++)
            #pragma unroll
            for (int b = 0; b < 4; b++) acc[a][b] = 0.f;

        for (int ic = 0; ic < 16; ic++) {
            #pragma unroll
            for (int k = 0; k < 9; k++) {
                int dy = k / 3, dx = k % 3;
                float wv = w2t[(ic * 9 + k) * 32 + oc];
                #pragma unroll
                for (int ph2 = 0; ph2 < 3; ph2++) {
                    #pragma unroll
                    for (int pt = 0; pt < 4; pt++) {
                        int y = 2 * ph2 + (pt >> 1) + dy;
                        int xx = 2 * pw2 + (pt & 1) + dx;
                        acc[ph2][pt] += wv * p1p[w][(ic * 8 + y) * 7 + xx];
                    }
                }
            }
        }
        float bias = b2s[oc];
        _Float16* fo = feat + (size_t)img * 192;
        #pragma unroll
        for (int ph2 = 0; ph2 < 3; ph2++) {
            float m = fmaxf(fmaxf(acc[ph2][0], acc[ph2][1]),
                            fmaxf(acc[ph2][2], acc[ph2][3]));
            fo[oc * 6 + ph2 * 2 + pw2] = (_Float16)fmaxf(0.f, m + bias);
        }
    }
}

// ---------------- Kernel B: gx = feat @ W_ih^T + bias via MFMA f16 ----------
__global__ __launch_bounds__(256) void gemm_gx_kernel(
    const _Float16* __restrict__ feat,  // [65536][192]
    const float* __restrict__ Wih,      // [1024][192]
    const float* __restrict__ bih,
    const float* __restrict__ bhh,
    _Float16* __restrict__ gx)          // [65536][1024]
{
    __shared__ uint4 As4[64][25];   // 25.6 KB, row stride 400 B
    __shared__ uint4 Bs4[64][25];   // 25.6 KB

    const int tid = threadIdx.x;
    const int n0 = blockIdx.x * 64;
    const int m0 = blockIdx.y * 64;

    #pragma unroll
    for (int it = 0; it < 6; it++) {
        int q = tid + it * 256;
        int m = q / 24, c = q % 24;
        As4[m][c] = *(const uint4*)(feat + (size_t)(m0 + m) * 192 + c * 8);
    }
    unsigned int* Bu = (unsigned int*)Bs4;
    #pragma unroll
    for (int it = 0; it < 24; it++) {
        int q = tid + it * 256;
        int n = q / 96, p = q % 96;
        Bu[n * 100 + p] = packf2(Wih + (size_t)(n0 + n) * 192 + 2 * p);
    }
    __syncthreads();

    const int wv = tid >> 6;
    const int lane = tid & 63;
    const int lm = lane & 15;
    const int lk = lane >> 4;

    f32x4 acc[4] = {{0.f, 0.f, 0.f, 0.f}, {0.f, 0.f, 0.f, 0.f},
                    {0.f, 0.f, 0.f, 0.f}, {0.f, 0.f, 0.f, 0.f}};

    #pragma unroll
    for (int ks = 0; ks < 6; ks++) {
        f16x8 a = __builtin_bit_cast(f16x8, As4[wv * 16 + lm][ks * 4 + lk]);
        #pragma unroll
        for (int j = 0; j < 4; j++) {
            f16x8 b = __builtin_bit_cast(f16x8, Bs4[j * 16 + lm][ks * 4 + lk]);
            acc[j] = __builtin_amdgcn_mfma_f32_16x16x32_f16(a, b, acc[j], 0, 0, 0);
        }
    }

    #pragma unroll
    for (int j = 0; j < 4; j++) {
        int n = n0 + j * 16 + lm;
        float bias = bih[n] + bhh[n];
        #pragma unroll
        for (int i = 0; i < 4; i++) {
            int m = m0 + wv * 16 + lk * 4 + i;
            gx[(size_t)m * 1024 + n] = (_Float16)(acc[j][i] + bias);
        }
    }
}

// ---------------- Kernel C: 512-step LSTM + classifier ----------------
// 128 blocks x 512 threads (8 waves, 2/SIMD). Thread t owns rows r0=t, r1=t+512.
// Per row: pairs 0..35 LDS (wl4, 144 KB) | 36..75 regs (wr0/wr1, 80 VGPR) |
// 76..127 streamed from pre-packed sw (uint4 [13][1024], coalesced, L2-hot).
// h broadcast via uniform-address ds_read_b128 (conflict-free).
__global__ __launch_bounds__(512, 2) void lstm_kernel(
    const _Float16* __restrict__ gx, // [128][512][1024]
    const float* __restrict__ Whh,   // [1024][256]
    const uint4* __restrict__ sw,    // [13][1024]
    const float* __restrict__ clsw,  // [64][256]
    const float* __restrict__ clsb,  // [64]
    float* __restrict__ out)         // [128][64]
{
    __shared__ uint4 wl4[9][1024];                     // 144 KB
    __shared__ __align__(16) _Float16 hbuf[2][256];    // 1 KB
    __shared__ float xg[512];                          // 2 KB

    const int t = threadIdx.x;
    const int b = blockIdx.x;
    const int r0 = t, r1 = t + 512;

    const float* w0 = Whh + (size_t)r0 * 256;
    const float* w1 = Whh + (size_t)r1 * 256;

    // LDS weights: pairs 0..35 (f32 elems 0..71)
    #pragma unroll
    for (int ch = 0; ch < 9; ch++) {
        wl4[ch][r0] = pack8(w0 + 8 * ch);
        wl4[ch][r1] = pack8(w1 + 8 * ch);
    }
    // register weights: pairs 36..75 (f32 elems 72..151)
    half2v wr0[40], wr1[40];
    #pragma unroll
    for (int q = 0; q < 40; q++) {
        wr0[q] = bch2(packf2(w0 + 72 + 2 * q));
        wr1[q] = bch2(packf2(w1 + 72 + 2 * q));
    }
    if (t < 256) hbuf[0][t] = (_Float16)0.f;
    __syncthreads();

    float c = 0.f;
    int cur = 0;
    const _Float16* gxb = gx + (size_t)b * 512 * 1024;
    float ga = (float)gxb[r0];
    float gb = (float)gxb[r1];

    for (int step = 0; step < 512; step++) {
        const _Float16* gxn = gxb + (size_t)((step + 1) & 511) * 1024;
        _Float16 na = gxn[r0];
        _Float16 nb = gxn[r1];

        float acc0 = ga, acc1 = gb;
        const uint4* hb4 = (const uint4*)&hbuf[cur][0];  // 32 chunks of 4 pairs

        // STREAM section first: issue global loads early, consume as they land.
        // chunks 19..31 of h <-> sw chunks 0..12
        #pragma unroll
        for (int sc = 0; sc < 13; sc++) {
            uint4 u0 = sw[sc * 1024 + r0];
            uint4 u1 = sw[sc * 1024 + r1];
            uint4 hv = hb4[19 + sc];
            acc0 = dot2f16(bch2(u0.x), bch2(hv.x), acc0);
            acc0 = dot2f16(bch2(u0.y), bch2(hv.y), acc0);
            acc0 = dot2f16(bch2(u0.z), bch2(hv.z), acc0);
            acc0 = dot2f16(bch2(u0.w), bch2(hv.w), acc0);
            acc1 = dot2f16(bch2(u1.x), bch2(hv.x), acc1);
            acc1 = dot2f16(bch2(u1.y), bch2(hv.y), acc1);
            acc1 = dot2f16(bch2(u1.z), bch2(hv.z), acc1);
            acc1 = dot2f16(bch2(u1.w), bch2(hv.w), acc1);
        }
        // LDS section: chunks 0..8
        #pragma unroll
        for (int ch = 0; ch < 9; ch++) {
            uint4 u0 = wl4[ch][r0];
            uint4 u1 = wl4[ch][r1];
            uint4 hv = hb4[ch];
            acc0 = dot2f16(bch2(u0.x), bch2(hv.x), acc0);
            acc0 = dot2f16(bch2(u0.y), bch2(hv.y), acc0);
            acc0 = dot2f16(bch2(u0.z), bch2(hv.z), acc0);
            acc0 = dot2f16(bch2(u0.w), bch2(hv.w), acc0);
            acc1 = dot2f16(bch2(u1.x), bch2(hv.x), acc1);
            acc1 = dot2f16(bch2(u1.y), bch2(hv.y), acc1);
            acc1 = dot2f16(bch2(u1.z), bch2(hv.z), acc1);
            acc1 = dot2f16(bch2(u1.w), bch2(hv.w), acc1);
        }
        // REG section: chunks 9..18, wr index q = 4*(c-9)+j
        #pragma unroll
        for (int cc = 0; cc < 10; cc++) {
            uint4 hv = hb4[9 + cc];
            acc0 = dot2f16(wr0[4 * cc + 0], bch2(hv.x), acc0);
            acc0 = dot2f16(wr0[4 * cc + 1], bch2(hv.y), acc0);
            acc0 = dot2f16(wr0[4 * cc + 2], bch2(hv.z), acc0);
            acc0 = dot2f16(wr0[4 * cc + 3], bch2(hv.w), acc0);
            acc1 = dot2f16(wr1[4 * cc + 0], bch2(hv.x), acc1);
            acc1 = dot2f16(wr1[4 * cc + 1], bch2(hv.y), acc1);
            acc1 = dot2f16(wr1[4 * cc + 2], bch2(hv.z), acc1);
            acc1 = dot2f16(wr1[4 * cc + 3], bch2(hv.w), acc1);
        }

        if (t >= 256) {           // acc0 = f_j, acc1 = o_j for j = t-256
            xg[t - 256] = acc0;
            xg[t] = acc1;
        }
        __syncthreads();
        if (t < 256) {            // acc0 = i_j, acc1 = g_j for j = t
            float i_ = 1.f / (1.f + __expf(-acc0));
            float g_ = 1.f - 2.f / (__expf(2.f * acc1) + 1.f);
            float f_ = 1.f / (1.f + __expf(-xg[t]));
            float o_ = 1.f / (1.f + __expf(-xg[t + 256]));
            c = f_ * c + i_ * g_;
            float th = 1.f - 2.f / (__expf(2.f * c) + 1.f);
            float h = o_ * th;
            hbuf[cur ^ 1][t] = (_Float16)h;
        }
        __syncthreads();
        cur ^= 1;
        ga = (float)na;
        gb = (float)nb;
    }

    if (t < 64) {
        const float* cw = clsw + t * 256;
        float s = clsb[t];
        for (int k = 0; k < 256; k++) s += cw[k] * (float)hbuf[cur][k];
        out[b * 64 + t] = s;
    }
}

extern "C" void kernel_launch(void* const* d_in, const int* in_sizes, int n_in,
                              void* d_out, int out_size, void* d_ws, size_t ws_size,
                              hipStream_t stream) {
    const float* x    = (const float*)d_in[0];
    const float* c1w  = (const float*)d_in[1];
    const float* c1b  = (const float*)d_in[2];
    const float* c2w  = (const float*)d_in[3];
    const float* c2b  = (const float*)d_in[4];
    const float* Wih  = (const float*)d_in[5];
    const float* bih  = (const float*)d_in[6];
    const float* Whh  = (const float*)d_in[7];
    const float* bhh  = (const float*)d_in[8];
    const float* clsw = (const float*)d_in[9];
    const float* clsb = (const float*)d_in[10];

    _Float16* feat = (_Float16*)d_ws;                   // 25.2 MB
    _Float16* gx   = feat + (size_t)65536 * 192;        // 134.2 MB
    uint4* sw      = (uint4*)(gx + (size_t)65536 * 1024); // 208 KB
    float* outp = (float*)d_out;

    hipLaunchKernelGGL(prepack_kernel, dim3(52), dim3(256), 0, stream, Whh, sw);
    hipLaunchKernelGGL(conv_kernel, dim3(16384), dim3(256), 0, stream,
                       x, c1w, c1b, c2w, c2b, feat);
    hipLaunchKernelGGL(gemm_gx_kernel, dim3(16, 1024), dim3(256), 0, stream,
                       feat, Wih, bih, bhh, gx);
    hipLaunchKernelGGL(lstm_kernel, dim3(128), dim3(512), 0, stream,
                       gx, Whh, sw, clsw, clsb, outp);
}